// Round 4
// baseline (5094.747 us; speedup 1.0000x reference)
//
#include <hip/hip_runtime.h>
#include <hip/hip_bf16.h>
#include <stdint.h>

#define H_  10
#define B_  16384
#define F_  4
#define D_  2048
#define C_  2

typedef __attribute__((ext_vector_type(8)))  short  short8;
typedef __attribute__((ext_vector_type(16))) float  floatx16;

typedef const uint32_t __attribute__((address_space(1))) gu32;
typedef uint32_t       __attribute__((address_space(3))) lu32;

__device__ __forceinline__ void async16(const void* g, void* l) {
    __builtin_amdgcn_global_load_lds((gu32*)g, (lu32*)l, 16, 0, 0);
}

__device__ __forceinline__ short8 bc8(uint4 v) { return __builtin_bit_cast(short8, v); }

// relu + round-half-up bf16 pack (hot path, proven numerics)
__device__ __forceinline__ uint32_t packbf(float a, float b) {
    a = fmaxf(a, 0.f); b = fmaxf(b, 0.f);
    const uint32_t ax = __builtin_bit_cast(uint32_t, a) + 0x8000u;
    const uint32_t bx = __builtin_bit_cast(uint32_t, b) + 0x8000u;
    return (ax >> 16) | (bx & 0xFFFF0000u);
}

// full-precision RNE pack (convert kernel only)
__device__ __forceinline__ uint32_t f2bf(float f) {
    union { float f; uint32_t u; } a; a.f = f;
    uint32_t u = a.u;
    u += 0x7FFF + ((u >> 16) & 1);
    return u >> 16;
}
__device__ __forceinline__ uint32_t pack2bf(float a, float b) {
    return f2bf(a) | (f2bf(b) << 16);
}

// ---------------------------------------------------------------------------
// ws layout (bytes) — total 237,502,464 (proven in-budget R1-R3):
//   0          : Bc    bf16 [H][4096][2048] (n-major, k-contig; n<2048 = W21,
//                                            n>=2048 = W22)      167,772,160
//   167772160  : acc31 f32 [H][B_][C_]                             1,310,720
//   169082880  : acc32 f32 [H][B_][C_]                             1,310,720
//   170393600  : h1t   bf16 [B_][2048]  (per-head, reused)        67,108,864
// ---------------------------------------------------------------------------

__global__ __launch_bounds__(256) void k_convert(
    const float* __restrict__ W21, const float* __restrict__ W22,
    uint16_t* __restrict__ Bc)
{
    __shared__ float tile[64][65];
    const int z = blockIdx.z;
    const int h = z % H_;
    const float* src = (z < H_ ? W21 : W22) + (size_t)h * D_ * D_;
    uint16_t*   dst  = Bc + (size_t)h * 2 * D_ * D_ + (z < H_ ? 0 : (size_t)D_ * D_);
    const int k0 = blockIdx.x * 64, n0 = blockIdx.y * 64;
    const int t = threadIdx.x;

    const int c4 = (t & 15) * 4;
    const int rb = (t >> 4) * 4;
#pragma unroll
    for (int i = 0; i < 4; i++) {
        const float4 v = *(const float4*)(src + (size_t)(k0 + rb + i) * D_ + n0 + c4);
        tile[rb + i][c4 + 0] = v.x; tile[rb + i][c4 + 1] = v.y;
        tile[rb + i][c4 + 2] = v.z; tile[rb + i][c4 + 3] = v.w;
    }
    __syncthreads();
    const int n = t >> 2;
    const int cb = (t & 3) * 2;
#pragma unroll
    for (int j = 0; j < 2; j++) {
        const int kk = (cb + j) * 8;
        uint32_t pk[4];
#pragma unroll
        for (int e = 0; e < 4; e++)
            pk[e] = pack2bf(tile[kk + 2 * e][n], tile[kk + 2 * e + 1][n]);
        *(uint4*)(dst + (size_t)(n0 + n) * D_ + k0 + kk) = make_uint4(pk[0], pk[1], pk[2], pk[3]);
    }
}

__global__ __launch_bounds__(256) void k_zero(uint4* p, int n4) {
    const int i = blockIdx.x * 256 + threadIdx.x;
    if (i < n4) p[i] = make_uint4(0u, 0u, 0u, 0u);
}

// ---------------------------------------------------------------------------
// h1 = relu(x @ W1[h] + b1[h])  -> bf16 [B_][2048], row-major k-contig
// ---------------------------------------------------------------------------
__global__ __launch_bounds__(256) void k_h1(
    const float* __restrict__ x, const float* __restrict__ W1,
    const float* __restrict__ b1, uint16_t* __restrict__ h1t, int h)
{
    const int t = threadIdx.x;
    const int kc = t & 127;            // 16-wide k chunk
    const int rh = t >> 7;             // 0,1
    const int k0 = kc * 16;
    const float* W1h = W1 + (size_t)h * F_ * D_;
    float w[4][16], bb[16];
#pragma unroll
    for (int f = 0; f < 4; f++)
#pragma unroll
        for (int j = 0; j < 16; j += 4) {
            const float4 v = *(const float4*)(W1h + f * D_ + k0 + j);
            w[f][j] = v.x; w[f][j+1] = v.y; w[f][j+2] = v.z; w[f][j+3] = v.w;
        }
#pragma unroll
    for (int j = 0; j < 16; j += 4) {
        const float4 v = *(const float4*)(b1 + (size_t)h * D_ + k0 + j);
        bb[j] = v.x; bb[j+1] = v.y; bb[j+2] = v.z; bb[j+3] = v.w;
    }
    const int rowBase = blockIdx.x * 16 + rh * 8;
#pragma unroll
    for (int rr = 0; rr < 8; rr++) {
        const int row = rowBase + rr;
        const float4 xv = *(const float4*)(x + (size_t)row * 4);
        uint32_t pk[8];
#pragma unroll
        for (int j = 0; j < 16; j += 2) {
            float aa = fmaf(xv.x, w[0][j], bb[j]);
            aa = fmaf(xv.y, w[1][j], aa);
            aa = fmaf(xv.z, w[2][j], aa);
            aa = fmaf(xv.w, w[3][j], aa);
            float bv = fmaf(xv.x, w[0][j+1], bb[j+1]);
            bv = fmaf(xv.y, w[1][j+1], bv);
            bv = fmaf(xv.z, w[2][j+1], bv);
            bv = fmaf(xv.w, w[3][j+1], bv);
            pk[j >> 1] = packbf(aa, bv);
        }
        uint16_t* d = h1t + (size_t)row * D_ + k0;
        *(uint4*)d       = make_uint4(pk[0], pk[1], pk[2], pk[3]);
        *(uint4*)(d + 8) = make_uint4(pk[4], pk[5], pk[6], pk[7]);
    }
}

// ---------------------------------------------------------------------------
// BM=128 x BN=256, BK=64, 256 threads (4 waves 1Mx4N), 80 KB LDS:
//   A single 16 KB (reg-staged 1 tile ahead: global->pa->ds_write),
//   B double 2x32 KB (async global_load_lds 1 tile ahead, counted overlap).
// 2 blocks/CU (2x80=160 KB) anti-phase + zero exposed stage latency: the one
// vmcnt(0) per K-tile waits loads issued a full compute phase earlier.
// MFMA 32x32x16 bf16; per-wave 128x64 = 4m x 2n frags.
// LDS swizzle (uint4 units): unit(row,c) = row*8 + (c ^ (row&7))  [0-conflict]
// via pre-swizzled global source + linear dest. Layouts identical to R3.
// ---------------------------------------------------------------------------
__global__ __launch_bounds__(256, 2) void k_gemm(
    const uint16_t* __restrict__ h1t, const uint16_t* __restrict__ Bcw,
    const float* __restrict__ b21, const float* __restrict__ b22,
    const float* __restrict__ W31, const float* __restrict__ W32,
    float* __restrict__ acc31, float* __restrict__ acc32, int h)
{
    extern __shared__ uint4 smem[];   // A:[0,1024) B0:[1024,3072) B1:[3072,5120)

    // XCD-contiguous M-slice: xcd owns m-tiles [xcd*16, xcd*16+16), sweeps n
    const int bid = blockIdx.x;
    const int xcd = bid & 7, idx = bid >> 3;
    const int mt = xcd * 16 + (idx & 15), nt = idx >> 4;
    const int mBase = mt * 128, nBase = nt * 256;   // nBase in concat [0,4096)

    const int t = threadIdx.x;
    const int lane = t & 63, wid = t >> 6;          // 4 waves; wid = n-chunk
    const int l31 = lane & 31, hi = lane >> 5;

    // staging: lane l handles row (i*32 + wid*8 + (l>>3)), global chunk (l&7)^(l>>3)
    const int srow   = lane >> 3;
    const int schunk = (lane & 7) ^ srow;

    const uint16_t* Ag = h1t + (size_t)(mBase + wid * 8 + srow) * D_ + schunk * 8;
    const uint16_t* Bg = Bcw + (size_t)h * (4096 * (size_t)D_)
                             + (size_t)(nBase + wid * 8 + srow) * D_ + schunk * 8;

    uint4 pa[4];
    auto loadA = [&](int kt) {
#pragma unroll
        for (int i = 0; i < 4; i++)
            pa[i] = *(const uint4*)(Ag + (size_t)(i * 32) * D_ + kt);
    };
    auto writeA = [&]() {
#pragma unroll
        for (int i = 0; i < 4; i++)
            smem[i * 256 + wid * 64 + lane] = pa[i];
    };
    auto stageB = [&](int buf, int kt) {
#pragma unroll
        for (int i = 0; i < 8; i++)
            async16(Bg + (size_t)(i * 32) * D_ + kt,
                    smem + 1024 + buf * 2048 + i * 256 + wid * 64);
    };

    floatx16 acc[4][2];
#pragma unroll
    for (int mi = 0; mi < 4; mi++)
#pragma unroll
        for (int nj = 0; nj < 2; nj++)
#pragma unroll
            for (int e = 0; e < 16; e++) acc[mi][nj][e] = 0.f;

    const int x7 = l31 & 7;

    // ---- prologue: B(0)->B[0], A(0)->regs; drain; A(0)->LDS; B(1)->B[1]; A(1)->regs
    stageB(0, 0);
    loadA(0);
    asm volatile("s_waitcnt vmcnt(0)" ::: "memory");
    __builtin_amdgcn_sched_barrier(0);
    writeA();
    stageB(1, 64);
    asm volatile("s_waitcnt lgkmcnt(0)" ::: "memory");
    __builtin_amdgcn_sched_barrier(0);
    loadA(64);
    __builtin_amdgcn_s_barrier();
    __builtin_amdgcn_sched_barrier(0);

    for (int tt = 0; tt < 32; ++tt) {
        const uint4* Bb = smem + 1024 + (tt & 1) * 2048;

        __builtin_amdgcn_s_setprio(1);
#pragma unroll
        for (int kk = 0; kk < 4; kk++) {
            const int cx = (kk * 2 + hi) ^ x7;
            short8 af[4], bf[2];
#pragma unroll
            for (int mi = 0; mi < 4; mi++)
                af[mi] = bc8(smem[(mi * 32 + l31) * 8 + cx]);
#pragma unroll
            for (int nj = 0; nj < 2; nj++)
                bf[nj] = bc8(Bb[(wid * 64 + nj * 32 + l31) * 8 + cx]);
#pragma unroll
            for (int mi = 0; mi < 4; mi++)
#pragma unroll
                for (int nj = 0; nj < 2; nj++)
                    acc[mi][nj] = __builtin_amdgcn_mfma_f32_32x32x16_bf16(
                        af[mi], bf[nj], acc[mi][nj], 0, 0, 0);
        }
        __builtin_amdgcn_s_setprio(0);
        if (tt == 31) break;

        __builtin_amdgcn_s_barrier();                       // LDS[t] reads done
        asm volatile("s_waitcnt vmcnt(0)" ::: "memory");    // t+1 (issued 1 compute ago) landed
        __builtin_amdgcn_sched_barrier(0);
        writeA();                                           // A(t+1) -> A-lds
        if (tt < 30) stageB(tt & 1, (tt + 2) * 64);         // B(t+2) -> just-freed buffer
        asm volatile("s_waitcnt lgkmcnt(0)" ::: "memory");  // A writes visible; pa free
        __builtin_amdgcn_sched_barrier(0);
        if (tt < 30) loadA((tt + 2) * 64);                  // A(t+2) -> regs
        __builtin_amdgcn_s_barrier();
        __builtin_amdgcn_sched_barrier(0);
    }

    // ---- Epilogue: bias + relu + (.)@W3[half] reduce over n, shuffle, atomics
    const int p    = nBase >> 11;          // 0: W21/W31 path, 1: W22/W32 path
    const int nloc = nBase & 2047;
    const float* b2p = (p ? b22 : b21) + (size_t)h * D_;
    const float* W3p = (p ? W32 : W31) + (size_t)h * D_ * C_;
    float* ab = (p ? acc32 : acc31) + (size_t)h * B_ * C_;

    float bs[2], w3x[2], w3y[2];
#pragma unroll
    for (int nj = 0; nj < 2; nj++) {
        const int e = nloc + wid * 64 + nj * 32 + l31;
        bs[nj] = b2p[e];
        const float2 w2 = *(const float2*)(W3p + e * 2);
        w3x[nj] = w2.x; w3y[nj] = w2.y;
    }
#pragma unroll
    for (int mi = 0; mi < 4; mi++)
#pragma unroll
        for (int r = 0; r < 16; r++) {
            const float v0 = fmaxf(acc[mi][0][r] + bs[0], 0.f);
            const float v1 = fmaxf(acc[mi][1][r] + bs[1], 0.f);
            float s0 = fmaf(v0, w3x[0], v1 * w3x[1]);
            float s1 = fmaf(v0, w3y[0], v1 * w3y[1]);
#pragma unroll
            for (int off = 1; off < 32; off <<= 1) {
                s0 += __shfl_xor(s0, off, 64);
                s1 += __shfl_xor(s1, off, 64);
            }
            if (l31 == 0) {
                const int row = mBase + mi * 32 + (r & 3) + 8 * (r >> 2) + 4 * hi;
                atomicAdd(&ab[row * C_ + 0], s0);
                atomicAdd(&ab[row * C_ + 1], s1);
            }
        }
}

// ---------------------------------------------------------------------------
// Finalize: biases, sigmoid head, CBF-QP correction, softmax-weighted mix
// ---------------------------------------------------------------------------
__global__ __launch_bounds__(256) void k_final(
    const float* __restrict__ x,
    const float* __restrict__ acc31, const float* __restrict__ acc32,
    const float* __restrict__ b31, const float* __restrict__ b32,
    const float* __restrict__ wt, const float* __restrict__ mean,
    const float* __restrict__ stdv, float* __restrict__ out)
{
    const int b = blockIdx.x * 256 + threadIdx.x;
    const float4 xb = *(const float4*)(x + (size_t)b * 4);
    const float px = xb.x * stdv[0] + mean[0];
    const float py = xb.y * stdv[1] + mean[1];
    const float th = xb.z * stdv[2] + mean[2];
    const float v  = xb.w * stdv[3] + mean[3];
    const float dx = px - 40.0f, dy = py - 15.0f;
    const float st = sinf(th), ct = cosf(th);
    const float barrier = dx * dx + dy * dy - 36.0f;
    const float bdot = 2.f * dx * v * ct + 2.f * dy * v * st;
    const float Lf2b = 2.f * v * v;
    const float G0 = -(-2.f * dx * v * st + 2.f * dy * v * ct);
    const float G1 = -(2.f * dx * ct + 2.f * dy * st);
    const float GG = G0 * G0 + G1 * G1;

    float we[H_];
    float wmax = wt[0];
    for (int h = 1; h < H_; h++) wmax = fmaxf(wmax, wt[h]);
    float wsum = 0.f;
    for (int h = 0; h < H_; h++) { we[h] = expf(wt[h] - wmax); wsum += we[h]; }

    float o0 = 0.f, o1 = 0.f;
#pragma unroll
    for (int h = 0; h < H_; h++) {
        const size_t idx = ((size_t)h * B_ + b) * 2;
        const float x310 = acc31[idx]     + b31[h * 2];
        const float x311 = acc31[idx + 1] + b31[h * 2 + 1];
        const float z0 = acc32[idx]     + b32[h * 2];
        const float z1 = acc32[idx + 1] + b32[h * 2 + 1];
        const float x320 = 4.f / (1.f + expf(-z0));
        const float x321 = 4.f / (1.f + expf(-z1));
        const float hr = Lf2b + (x320 + x321) * bdot + x320 * x321 * barrier;
        const float Gu = G0 * x310 + G1 * x311;
        const float lam = fmaxf(Gu - hr, 0.f) / GG;
        o0 += we[h] * (x310 - lam * G0);
        o1 += we[h] * (x311 - lam * G1);
    }
    out[b * 2]     = o0 / wsum;
    out[b * 2 + 1] = o1 / wsum;
}

extern "C" void kernel_launch(void* const* d_in, const int* in_sizes, int n_in,
                              void* d_out, int out_size, void* d_ws, size_t ws_size,
                              hipStream_t stream)
{
    const float* x    = (const float*)d_in[0];
    const float* W1   = (const float*)d_in[1];
    const float* b1   = (const float*)d_in[2];
    const float* W21  = (const float*)d_in[3];
    const float* b21  = (const float*)d_in[4];
    const float* W22  = (const float*)d_in[5];
    const float* b22  = (const float*)d_in[6];
    const float* W31  = (const float*)d_in[7];
    const float* b31  = (const float*)d_in[8];
    const float* W32  = (const float*)d_in[9];
    const float* b32  = (const float*)d_in[10];
    const float* wt   = (const float*)d_in[11];
    const float* mean = (const float*)d_in[12];
    const float* stdv = (const float*)d_in[13];
    float* out = (float*)d_out;

    char* ws = (char*)d_ws;
    uint16_t* Bc   = (uint16_t*)(ws);
    float* acc31   = (float*)(ws + 167772160);
    float* acc32   = (float*)(ws + 169082880);
    uint16_t* h1t  = (uint16_t*)(ws + 170393600);

    static bool attr_done = false;
    if (!attr_done) {
        hipFuncSetAttribute(reinterpret_cast<const void*>(k_gemm),
                            hipFuncAttributeMaxDynamicSharedMemorySize, 81920);
        attr_done = true;
    }

    k_convert<<<dim3(32, 32, 20), 256, 0, stream>>>(W21, W22, Bc);
    k_zero<<<dim3(640), 256, 0, stream>>>((uint4*)acc31, 163840);
    for (int h = 0; h < H_; ++h) {
        k_h1<<<dim3(1024), 256, 0, stream>>>(x, W1, b1, h1t, h);
        k_gemm<<<dim3(2048), 256, 81920, stream>>>(h1t, Bc, b21, b22, W31, W32,
                                                   acc31, acc32, h);
    }
    k_final<<<dim3(64), 256, 0, stream>>>(x, acc31, acc32, b31, b32, wt, mean, stdv, out);
}

// Round 5
// 3681.978 us; speedup vs baseline: 1.3837x; 1.3837x over previous
//
#include <hip/hip_runtime.h>
#include <hip/hip_bf16.h>
#include <stdint.h>

#define H_  10
#define B_  16384
#define F_  4
#define D_  2048
#define C_  2

typedef __attribute__((ext_vector_type(8)))  short  short8;
typedef __attribute__((ext_vector_type(16))) float  floatx16;

typedef const uint32_t __attribute__((address_space(1))) gu32;
typedef uint32_t       __attribute__((address_space(3))) lu32;

__device__ __forceinline__ void async16(const void* g, void* l) {
    __builtin_amdgcn_global_load_lds((gu32*)g, (lu32*)l, 16, 0, 0);
}

__device__ __forceinline__ short8 bc8(uint4 v) { return __builtin_bit_cast(short8, v); }

// relu + round-half-up bf16 pack (hot path, proven numerics)
__device__ __forceinline__ uint32_t packbf(float a, float b) {
    a = fmaxf(a, 0.f); b = fmaxf(b, 0.f);
    const uint32_t ax = __builtin_bit_cast(uint32_t, a) + 0x8000u;
    const uint32_t bx = __builtin_bit_cast(uint32_t, b) + 0x8000u;
    return (ax >> 16) | (bx & 0xFFFF0000u);
}

// full-precision RNE pack (convert kernel only)
__device__ __forceinline__ uint32_t f2bf(float f) {
    union { float f; uint32_t u; } a; a.f = f;
    uint32_t u = a.u;
    u += 0x7FFF + ((u >> 16) & 1);
    return u >> 16;
}
__device__ __forceinline__ uint32_t pack2bf(float a, float b) {
    return f2bf(a) | (f2bf(b) << 16);
}

// ---------------------------------------------------------------------------
// ws layout (bytes) — total 237,502,464 (proven in-budget R1-R4):
//   0          : Bc    bf16 [H][4096][2048] (n-major, k-contig; n<2048 = W21,
//                                            n>=2048 = W22)      167,772,160
//   167772160  : acc31 f32 [H][B_][C_]                             1,310,720
//   169082880  : acc32 f32 [H][B_][C_]                             1,310,720
//   170393600  : h1t   bf16 [B_][2048]  (per-head, reused)        67,108,864
// ---------------------------------------------------------------------------

__global__ __launch_bounds__(256) void k_convert(
    const float* __restrict__ W21, const float* __restrict__ W22,
    uint16_t* __restrict__ Bc)
{
    __shared__ float tile[64][65];
    const int z = blockIdx.z;
    const int h = z % H_;
    const float* src = (z < H_ ? W21 : W22) + (size_t)h * D_ * D_;
    uint16_t*   dst  = Bc + (size_t)h * 2 * D_ * D_ + (z < H_ ? 0 : (size_t)D_ * D_);
    const int k0 = blockIdx.x * 64, n0 = blockIdx.y * 64;
    const int t = threadIdx.x;

    const int c4 = (t & 15) * 4;
    const int rb = (t >> 4) * 4;
#pragma unroll
    for (int i = 0; i < 4; i++) {
        const float4 v = *(const float4*)(src + (size_t)(k0 + rb + i) * D_ + n0 + c4);
        tile[rb + i][c4 + 0] = v.x; tile[rb + i][c4 + 1] = v.y;
        tile[rb + i][c4 + 2] = v.z; tile[rb + i][c4 + 3] = v.w;
    }
    __syncthreads();
    const int n = t >> 2;
    const int cb = (t & 3) * 2;
#pragma unroll
    for (int j = 0; j < 2; j++) {
        const int kk = (cb + j) * 8;
        uint32_t pk[4];
#pragma unroll
        for (int e = 0; e < 4; e++)
            pk[e] = pack2bf(tile[kk + 2 * e][n], tile[kk + 2 * e + 1][n]);
        *(uint4*)(dst + (size_t)(n0 + n) * D_ + k0 + kk) = make_uint4(pk[0], pk[1], pk[2], pk[3]);
    }
}

__global__ __launch_bounds__(256) void k_zero(uint4* p, int n4) {
    const int i = blockIdx.x * 256 + threadIdx.x;
    if (i < n4) p[i] = make_uint4(0u, 0u, 0u, 0u);
}

// ---------------------------------------------------------------------------
// h1 = relu(x @ W1[h] + b1[h])  -> bf16 [B_][2048], row-major k-contig
// ---------------------------------------------------------------------------
__global__ __launch_bounds__(256) void k_h1(
    const float* __restrict__ x, const float* __restrict__ W1,
    const float* __restrict__ b1, uint16_t* __restrict__ h1t, int h)
{
    const int t = threadIdx.x;
    const int kc = t & 127;            // 16-wide k chunk
    const int rh = t >> 7;             // 0,1
    const int k0 = kc * 16;
    const float* W1h = W1 + (size_t)h * F_ * D_;
    float w[4][16], bb[16];
#pragma unroll
    for (int f = 0; f < 4; f++)
#pragma unroll
        for (int j = 0; j < 16; j += 4) {
            const float4 v = *(const float4*)(W1h + f * D_ + k0 + j);
            w[f][j] = v.x; w[f][j+1] = v.y; w[f][j+2] = v.z; w[f][j+3] = v.w;
        }
#pragma unroll
    for (int j = 0; j < 16; j += 4) {
        const float4 v = *(const float4*)(b1 + (size_t)h * D_ + k0 + j);
        bb[j] = v.x; bb[j+1] = v.y; bb[j+2] = v.z; bb[j+3] = v.w;
    }
    const int rowBase = blockIdx.x * 16 + rh * 8;
#pragma unroll
    for (int rr = 0; rr < 8; rr++) {
        const int row = rowBase + rr;
        const float4 xv = *(const float4*)(x + (size_t)row * 4);
        uint32_t pk[8];
#pragma unroll
        for (int j = 0; j < 16; j += 2) {
            float aa = fmaf(xv.x, w[0][j], bb[j]);
            aa = fmaf(xv.y, w[1][j], aa);
            aa = fmaf(xv.z, w[2][j], aa);
            aa = fmaf(xv.w, w[3][j], aa);
            float bv = fmaf(xv.x, w[0][j+1], bb[j+1]);
            bv = fmaf(xv.y, w[1][j+1], bv);
            bv = fmaf(xv.z, w[2][j+1], bv);
            bv = fmaf(xv.w, w[3][j+1], bv);
            pk[j >> 1] = packbf(aa, bv);
        }
        uint16_t* d = h1t + (size_t)row * D_ + k0;
        *(uint4*)d       = make_uint4(pk[0], pk[1], pk[2], pk[3]);
        *(uint4*)(d + 8) = make_uint4(pk[4], pk[5], pk[6], pk[7]);
    }
}

// ---------------------------------------------------------------------------
// BM=128 x BN=256, BK=32, 256 threads (4 waves 1Mx4N), 48 KB STATIC LDS,
// full double-buffer: A 2x8KB + B 2x16KB. 2 blocks/CU (96 KB) + zero exposed
// stage latency: stage(t+2) issued at iter bottom, waited (vmcnt(6)) at iter
// t+2 top — one full iteration (~1.6k cyc) of in-flight time. No register
// staging (no spill risk), one counted vmcnt + 2 raw barriers per iter.
//
// LDS tile layout (uint4 units), 128B row-PAIR stride to keep ds_read_b128
// bank-balanced at BK=32:  rp=r>>1, u=(((c<<1)|(r&1)) ^ (rp&7)),
// unit = rp*8 + u   (r = row in tile, c = 16B k-chunk in [0,4)).
// Achieved via pre-swizzled per-lane GLOBAL source + linear LDS dest.
// Bank check: 8 lanes per 4-bank group per wave instr (same balance as R3).
// MFMA 32x32x16; per-wave 128x64 out = 4m x 2n frags. Epilogue = R3 verbatim.
// ---------------------------------------------------------------------------
__global__ __launch_bounds__(256, 2) void k_gemm(
    const uint16_t* __restrict__ h1t, const uint16_t* __restrict__ Bcw,
    const float* __restrict__ b21, const float* __restrict__ b22,
    const float* __restrict__ W31, const float* __restrict__ W32,
    float* __restrict__ acc31, float* __restrict__ acc32, int h)
{
    __shared__ uint4 smem[3072];   // A: [0,1024) (2 bufs x 512), B: [1024,3072) (2 x 1024)

    // XCD-contiguous M-slice: xcd owns m-tiles [xcd*16, xcd*16+16), sweeps n
    const int bid = blockIdx.x;
    const int xcd = bid & 7, idx = bid >> 3;
    const int mt = xcd * 16 + (idx & 15), nt = idx >> 4;
    const int mBase = mt * 128, nBase = nt * 256;   // nBase in concat [0,4096)

    const int t = threadIdx.x;
    const int lane = t & 63, wid = t >> 6;          // 4 waves; wid = n-chunk
    const int l31 = lane & 31, hi = lane >> 5;

    // ---- staging source offsets (pre-swizzled global for linear LDS dest)
    // dest unit (A, j): j*256 + t ; (B, j): j*256 + t.  Inverse of the tile map:
    //   rp = unit>>3, u = unit&7, uu = u ^ (rp&7), row = rp*2 + (uu&1), c = uu>>1
    const uint16_t* Abase = h1t + (size_t)mBase * D_;
    const uint16_t* Bbase = Bcw + (size_t)h * (4096 * (size_t)D_) + (size_t)nBase * D_;
    int aoff[2], boff[4];
#pragma unroll
    for (int j = 0; j < 2; j++) {
        const int unit = j * 256 + t;
        const int rp = unit >> 3, uu = (unit & 7) ^ (rp & 7);
        aoff[j] = (rp * 2 + (uu & 1)) * D_ + (uu >> 1) * 8;
    }
#pragma unroll
    for (int j = 0; j < 4; j++) {
        const int unit = j * 256 + t;
        const int rp = unit >> 3, uu = (unit & 7) ^ (rp & 7);
        boff[j] = (rp * 2 + (uu & 1)) * D_ + (uu >> 1) * 8;
    }
    const int wbase = wid * 64;   // wave-uniform part of dest unit

    auto stageTile = [&](int buf, int kt) {
#pragma unroll
        for (int j = 0; j < 2; j++)
            async16(Abase + aoff[j] + kt, smem + buf * 512 + j * 256 + wbase);
#pragma unroll
        for (int j = 0; j < 4; j++)
            async16(Bbase + boff[j] + kt, smem + 1024 + buf * 1024 + j * 256 + wbase);
    };

    // ---- read geometry
    const int rpl = l31 >> 1;           // row-pair within a 32-row frag block
    const int par = l31 & 1;
    const int x7p = rpl & 7;

    floatx16 acc[4][2];
#pragma unroll
    for (int mi = 0; mi < 4; mi++)
#pragma unroll
        for (int nj = 0; nj < 2; nj++)
#pragma unroll
            for (int e = 0; e < 16; e++) acc[mi][nj][e] = 0.f;

    // ---- prologue: tiles 0,1 staged; vmcnt(6) at iter 0 waits tile 0 only
    stageTile(0, 0);
    stageTile(1, 32);

    for (int tt = 0; tt < 64; ++tt) {
        if (tt == 63) { asm volatile("s_waitcnt vmcnt(0)" ::: "memory"); }
        else          { asm volatile("s_waitcnt vmcnt(6)" ::: "memory"); }
        __builtin_amdgcn_sched_barrier(0);
        __builtin_amdgcn_s_barrier();          // bar1: everyone's tile-t staged

        const int ab = (tt & 1) * 512;
        const int bb = 1024 + (tt & 1) * 1024;

        __builtin_amdgcn_s_setprio(1);
#pragma unroll
        for (int kk = 0; kk < 2; kk++) {
            const int u = ((((kk * 2 + hi) << 1) | par) ^ x7p);
            short8 af[4], bf[2];
#pragma unroll
            for (int mi = 0; mi < 4; mi++)
                af[mi] = bc8(smem[ab + (mi * 16 + rpl) * 8 + u]);
#pragma unroll
            for (int nj = 0; nj < 2; nj++)
                bf[nj] = bc8(smem[bb + (wid * 32 + nj * 16 + rpl) * 8 + u]);
#pragma unroll
            for (int mi = 0; mi < 4; mi++)
#pragma unroll
                for (int nj = 0; nj < 2; nj++)
                    acc[mi][nj] = __builtin_amdgcn_mfma_f32_32x32x16_bf16(
                        af[mi], bf[nj], acc[mi][nj], 0, 0, 0);
        }
        __builtin_amdgcn_s_setprio(0);

        __builtin_amdgcn_s_barrier();          // bar2: all waves' reads of buf done
        __builtin_amdgcn_sched_barrier(0);
        if (tt < 62) stageTile(tt & 1, (tt + 2) * 32);   // tile t+2 -> freed buffer
    }

    // ---- Epilogue: bias + relu + (.)@W3[half] reduce over n, shuffle, atomics
    const int p    = nBase >> 11;          // 0: W21/W31 path, 1: W22/W32 path
    const int nloc = nBase & 2047;
    const float* b2p = (p ? b22 : b21) + (size_t)h * D_;
    const float* W3p = (p ? W32 : W31) + (size_t)h * D_ * C_;
    float* ab2 = (p ? acc32 : acc31) + (size_t)h * B_ * C_;

    float bs[2], w3x[2], w3y[2];
#pragma unroll
    for (int nj = 0; nj < 2; nj++) {
        const int e = nloc + wid * 64 + nj * 32 + l31;
        bs[nj] = b2p[e];
        const float2 w2 = *(const float2*)(W3p + e * 2);
        w3x[nj] = w2.x; w3y[nj] = w2.y;
    }
#pragma unroll
    for (int mi = 0; mi < 4; mi++)
#pragma unroll
        for (int r = 0; r < 16; r++) {
            const float v0 = fmaxf(acc[mi][0][r] + bs[0], 0.f);
            const float v1 = fmaxf(acc[mi][1][r] + bs[1], 0.f);
            float s0 = fmaf(v0, w3x[0], v1 * w3x[1]);
            float s1 = fmaf(v0, w3y[0], v1 * w3y[1]);
#pragma unroll
            for (int off = 1; off < 32; off <<= 1) {
                s0 += __shfl_xor(s0, off, 64);
                s1 += __shfl_xor(s1, off, 64);
            }
            if (l31 == 0) {
                const int row = mBase + mi * 32 + (r & 3) + 8 * (r >> 2) + 4 * hi;
                atomicAdd(&ab2[row * C_ + 0], s0);
                atomicAdd(&ab2[row * C_ + 1], s1);
            }
        }
}

// ---------------------------------------------------------------------------
// Finalize: biases, sigmoid head, CBF-QP correction, softmax-weighted mix
// ---------------------------------------------------------------------------
__global__ __launch_bounds__(256) void k_final(
    const float* __restrict__ x,
    const float* __restrict__ acc31, const float* __restrict__ acc32,
    const float* __restrict__ b31, const float* __restrict__ b32,
    const float* __restrict__ wt, const float* __restrict__ mean,
    const float* __restrict__ stdv, float* __restrict__ out)
{
    const int b = blockIdx.x * 256 + threadIdx.x;
    const float4 xb = *(const float4*)(x + (size_t)b * 4);
    const float px = xb.x * stdv[0] + mean[0];
    const float py = xb.y * stdv[1] + mean[1];
    const float th = xb.z * stdv[2] + mean[2];
    const float v  = xb.w * stdv[3] + mean[3];
    const float dx = px - 40.0f, dy = py - 15.0f;
    const float st = sinf(th), ct = cosf(th);
    const float barrier = dx * dx + dy * dy - 36.0f;
    const float bdot = 2.f * dx * v * ct + 2.f * dy * v * st;
    const float Lf2b = 2.f * v * v;
    const float G0 = -(-2.f * dx * v * st + 2.f * dy * v * ct);
    const float G1 = -(2.f * dx * ct + 2.f * dy * st);
    const float GG = G0 * G0 + G1 * G1;

    float we[H_];
    float wmax = wt[0];
    for (int h = 1; h < H_; h++) wmax = fmaxf(wmax, wt[h]);
    float wsum = 0.f;
    for (int h = 0; h < H_; h++) { we[h] = expf(wt[h] - wmax); wsum += we[h]; }

    float o0 = 0.f, o1 = 0.f;
#pragma unroll
    for (int h = 0; h < H_; h++) {
        const size_t idx = ((size_t)h * B_ + b) * 2;
        const float x310 = acc31[idx]     + b31[h * 2];
        const float x311 = acc31[idx + 1] + b31[h * 2 + 1];
        const float z0 = acc32[idx]     + b32[h * 2];
        const float z1 = acc32[idx + 1] + b32[h * 2 + 1];
        const float x320 = 4.f / (1.f + expf(-z0));
        const float x321 = 4.f / (1.f + expf(-z1));
        const float hr = Lf2b + (x320 + x321) * bdot + x320 * x321 * barrier;
        const float Gu = G0 * x310 + G1 * x311;
        const float lam = fmaxf(Gu - hr, 0.f) / GG;
        o0 += we[h] * (x310 - lam * G0);
        o1 += we[h] * (x311 - lam * G1);
    }
    out[b * 2]     = o0 / wsum;
    out[b * 2 + 1] = o1 / wsum;
}

extern "C" void kernel_launch(void* const* d_in, const int* in_sizes, int n_in,
                              void* d_out, int out_size, void* d_ws, size_t ws_size,
                              hipStream_t stream)
{
    const float* x    = (const float*)d_in[0];
    const float* W1   = (const float*)d_in[1];
    const float* b1   = (const float*)d_in[2];
    const float* W21  = (const float*)d_in[3];
    const float* b21  = (const float*)d_in[4];
    const float* W22  = (const float*)d_in[5];
    const float* b22  = (const float*)d_in[6];
    const float* W31  = (const float*)d_in[7];
    const float* b31  = (const float*)d_in[8];
    const float* W32  = (const float*)d_in[9];
    const float* b32  = (const float*)d_in[10];
    const float* wt   = (const float*)d_in[11];
    const float* mean = (const float*)d_in[12];
    const float* stdv = (const float*)d_in[13];
    float* out = (float*)d_out;

    char* ws = (char*)d_ws;
    uint16_t* Bc   = (uint16_t*)(ws);
    float* acc31   = (float*)(ws + 167772160);
    float* acc32   = (float*)(ws + 169082880);
    uint16_t* h1t  = (uint16_t*)(ws + 170393600);

    k_convert<<<dim3(32, 32, 20), 256, 0, stream>>>(W21, W22, Bc);
    k_zero<<<dim3(640), 256, 0, stream>>>((uint4*)acc31, 163840);
    for (int h = 0; h < H_; ++h) {
        k_h1<<<dim3(1024), 256, 0, stream>>>(x, W1, b1, h1t, h);
        k_gemm<<<dim3(2048), 256, 0, stream>>>(h1t, Bc, b21, b22, W31, W32,
                                               acc31, acc32, h);
    }
    k_final<<<dim3(64), 256, 0, stream>>>(x, acc31, acc32, b31, b32, wt, mean, stdv, out);
}

// Round 6
// 3400.447 us; speedup vs baseline: 1.4983x; 1.0828x over previous
//
#include <hip/hip_runtime.h>
#include <hip/hip_bf16.h>
#include <stdint.h>

#define H_  10
#define B_  16384
#define F_  4
#define D_  2048
#define C_  2

typedef __attribute__((ext_vector_type(8)))  short  short8;
typedef __attribute__((ext_vector_type(16))) float  floatx16;

typedef const uint32_t __attribute__((address_space(1))) gu32;
typedef uint32_t       __attribute__((address_space(3))) lu32;

__device__ __forceinline__ void async16(const void* g, void* l) {
    __builtin_amdgcn_global_load_lds((gu32*)g, (lu32*)l, 16, 0, 0);
}

__device__ __forceinline__ short8 bc8(uint4 v) { return __builtin_bit_cast(short8, v); }

// relu + round-half-up bf16 pack (hot path, proven numerics)
__device__ __forceinline__ uint32_t packbf(float a, float b) {
    a = fmaxf(a, 0.f); b = fmaxf(b, 0.f);
    const uint32_t ax = __builtin_bit_cast(uint32_t, a) + 0x8000u;
    const uint32_t bx = __builtin_bit_cast(uint32_t, b) + 0x8000u;
    return (ax >> 16) | (bx & 0xFFFF0000u);
}

// full-precision RNE pack (convert kernel only)
__device__ __forceinline__ uint32_t f2bf(float f) {
    union { float f; uint32_t u; } a; a.f = f;
    uint32_t u = a.u;
    u += 0x7FFF + ((u >> 16) & 1);
    return u >> 16;
}
__device__ __forceinline__ uint32_t pack2bf(float a, float b) {
    return f2bf(a) | (f2bf(b) << 16);
}

// ---------------------------------------------------------------------------
// ws layout (bytes) — total 237,502,464 (proven in-budget R1-R5):
//   0          : Bc bf16 [H][4096-n][2048-k] in FRAGMENT-MAJOR order:
//                elem(n,k) at  (n>>5)*65536 + (k>>4)*512 + ((k>>3)&1)*256
//                             + (n&31)*8 + (k&7)
//                (n<2048 = W21 half, n>=2048 = W22 half)      167,772,160
//   167772160  : acc31 f32 [H][B_][C_]                          1,310,720
//   169082880  : acc32 f32 [H][B_][C_]                          1,310,720
//   170393600  : h1t   bf16 [B_][2048] row-major (per-head)    67,108,864
// ---------------------------------------------------------------------------

__global__ __launch_bounds__(256) void k_convert(
    const float* __restrict__ W21, const float* __restrict__ W22,
    uint16_t* __restrict__ Bc)
{
    __shared__ float tile[64][65];
    const int z = blockIdx.z;
    const int h = z % H_;
    const float* src = (z < H_ ? W21 : W22) + (size_t)h * D_ * D_;
    uint16_t*   dst  = Bc + (size_t)h * 2 * D_ * D_ + (z < H_ ? 0 : (size_t)D_ * D_);
    const int k0 = blockIdx.x * 64, n0 = blockIdx.y * 64;
    const int t = threadIdx.x;

    const int c4 = (t & 15) * 4;
    const int rb = (t >> 4) * 4;
#pragma unroll
    for (int i = 0; i < 4; i++) {
        const float4 v = *(const float4*)(src + (size_t)(k0 + rb + i) * D_ + n0 + c4);
        tile[rb + i][c4 + 0] = v.x; tile[rb + i][c4 + 1] = v.y;
        tile[rb + i][c4 + 2] = v.z; tile[rb + i][c4 + 3] = v.w;
    }
    __syncthreads();
    const int n = t >> 2;
    const int cb = (t & 3) * 2;
#pragma unroll
    for (int j = 0; j < 2; j++) {
        const int kk = (cb + j) * 8;
        uint32_t pk[4];
#pragma unroll
        for (int e = 0; e < 4; e++)
            pk[e] = pack2bf(tile[kk + 2 * e][n], tile[kk + 2 * e + 1][n]);
        const int N = n0 + n, K = k0 + kk;
        const size_t off = (size_t)(N >> 5) * 65536 + (size_t)(K >> 4) * 512
                         + (size_t)((K >> 3) & 1) * 256 + (size_t)(N & 31) * 8;
        *(uint4*)(dst + off) = make_uint4(pk[0], pk[1], pk[2], pk[3]);
    }
}

__global__ __launch_bounds__(256) void k_zero(uint4* p, int n4) {
    const int i = blockIdx.x * 256 + threadIdx.x;
    if (i < n4) p[i] = make_uint4(0u, 0u, 0u, 0u);
}

// ---------------------------------------------------------------------------
// h1 = relu(x @ W1[h] + b1[h])  -> bf16 [B_][2048], row-major k-contig
// ---------------------------------------------------------------------------
__global__ __launch_bounds__(256) void k_h1(
    const float* __restrict__ x, const float* __restrict__ W1,
    const float* __restrict__ b1, uint16_t* __restrict__ h1t, int h)
{
    const int t = threadIdx.x;
    const int kc = t & 127;            // 16-wide k chunk
    const int rh = t >> 7;             // 0,1
    const int k0 = kc * 16;
    const float* W1h = W1 + (size_t)h * F_ * D_;
    float w[4][16], bb[16];
#pragma unroll
    for (int f = 0; f < 4; f++)
#pragma unroll
        for (int j = 0; j < 16; j += 4) {
            const float4 v = *(const float4*)(W1h + f * D_ + k0 + j);
            w[f][j] = v.x; w[f][j+1] = v.y; w[f][j+2] = v.z; w[f][j+3] = v.w;
        }
#pragma unroll
    for (int j = 0; j < 16; j += 4) {
        const float4 v = *(const float4*)(b1 + (size_t)h * D_ + k0 + j);
        bb[j] = v.x; bb[j+1] = v.y; bb[j+2] = v.z; bb[j+3] = v.w;
    }
    const int rowBase = blockIdx.x * 16 + rh * 8;
#pragma unroll
    for (int rr = 0; rr < 8; rr++) {
        const int row = rowBase + rr;
        const float4 xv = *(const float4*)(x + (size_t)row * 4);
        uint32_t pk[8];
#pragma unroll
        for (int j = 0; j < 16; j += 2) {
            float aa = fmaf(xv.x, w[0][j], bb[j]);
            aa = fmaf(xv.y, w[1][j], aa);
            aa = fmaf(xv.z, w[2][j], aa);
            aa = fmaf(xv.w, w[3][j], aa);
            float bv = fmaf(xv.x, w[0][j+1], bb[j+1]);
            bv = fmaf(xv.y, w[1][j+1], bv);
            bv = fmaf(xv.z, w[2][j+1], bv);
            bv = fmaf(xv.w, w[3][j+1], bv);
            pk[j >> 1] = packbf(aa, bv);
        }
        uint16_t* d = h1t + (size_t)row * D_ + k0;
        *(uint4*)d       = make_uint4(pk[0], pk[1], pk[2], pk[3]);
        *(uint4*)(d + 8) = make_uint4(pk[4], pk[5], pk[6], pk[7]);
    }
}

// ---------------------------------------------------------------------------
// BM=128 x BN=256, BK=64, 256 threads (4 waves 1Mx4N), 32 KB static LDS.
// A: LDS double-buffer (2x16 KB) via global_load_lds, counted vmcnt(12) —
//    each wait targets loads issued a full K-iter earlier (zero exposed lat).
// B: NO LDS (zero intra-block reuse) — direct global->reg, fragment-major
//    layout makes each B-frag load one fully-coalesced 1 KB wave read.
//    Register double-buffer one K-tile ahead (static unroll-2, rule #20).
// 2 blocks/CU (VGPR-limited, launch_bounds(256,2)) anti-phase on top.
// A LDS swizzle: unit = row*8 + (chunk ^ (row&7) ^ ((row>>3)&3)) — each
// 8-lane ds_read_b128 group covers all 32 banks (conflict-free).
// MFMA 32x32x16; per-wave 128x64 out = 4m x 2n frags. Epilogue = R3 verbatim.
// vmcnt(12) derivation: younger-than-A(t) = B(t)[8] + A(t+1)[4] = 12; tail
// indices clamped so the count stays uniform (redundant loads are harmless).
// ---------------------------------------------------------------------------
__global__ __launch_bounds__(256, 2) void k_gemm(
    const uint16_t* __restrict__ h1t, const uint16_t* __restrict__ Bcw,
    const float* __restrict__ b21, const float* __restrict__ b22,
    const float* __restrict__ W31, const float* __restrict__ W32,
    float* __restrict__ acc31, float* __restrict__ acc32, int h)
{
    __shared__ uint4 smemA[2048];   // 2 bufs x 1024 units (16 KB each)

    // XCD-contiguous M-slice: xcd owns m-tiles [xcd*16, xcd*16+16), sweeps n
    const int bid = blockIdx.x;
    const int xcd = bid & 7, idx = bid >> 3;
    const int mt = xcd * 16 + (idx & 15), nt = idx >> 4;
    const int mBase = mt * 128, nBase = nt * 256;   // nBase in concat [0,4096)

    const int t = threadIdx.x;
    const int lane = t & 63, wid = t >> 6;          // 4 waves; wid = n-chunk
    const int l31 = lane & 31, hi = lane >> 5;

    // ---- A staging: dest unit j*256+t (linear), source pre-swizzled
    const uint16_t* Abase = h1t + (size_t)mBase * D_;
    int aoff[4];
#pragma unroll
    for (int j = 0; j < 4; j++) {
        const int unit = j * 256 + t;
        const int row = unit >> 3;
        const int cc = (unit & 7) ^ (row & 7) ^ ((row >> 3) & 3);
        aoff[j] = row * D_ + cc * 8;
    }
    const int wbase = wid * 64;

    auto stageA = [&](int buf, int kt) {
#pragma unroll
        for (int j = 0; j < 4; j++)
            async16(Abase + aoff[j] + kt, smemA + buf * 1024 + j * 256 + wbase);
    };

    // ---- B direct-load pointers (fragment-major layout)
    const uint16_t* Bhead = Bcw + (size_t)h * (4096 * (size_t)D_);
    const uint16_t* bptr[2];
#pragma unroll
    for (int nj = 0; nj < 2; nj++) {
        const int nf = (nBase >> 5) + wid * 2 + nj;
        bptr[nj] = Bhead + (size_t)nf * 65536 + (size_t)hi * 256 + (size_t)l31 * 8;
    }

    floatx16 acc[4][2];
#pragma unroll
    for (int mi = 0; mi < 4; mi++)
#pragma unroll
        for (int nj = 0; nj < 2; nj++)
#pragma unroll
            for (int e = 0; e < 16; e++) acc[mi][nj][e] = 0.f;

    uint4 bA[2][4], bB[2][4];
    const int x7 = l31 & 7, s3 = l31 >> 3;

    auto halfiter = [&](int tt, uint4 (&bcur)[2][4], uint4 (&bnxt)[2][4]) {
        asm volatile("s_waitcnt vmcnt(12)" ::: "memory");   // A(tt) landed
        __builtin_amdgcn_sched_barrier(0);
        __builtin_amdgcn_s_barrier();                       // all waves' A(tt) visible
        const int tn = (tt < 31) ? tt + 1 : 31;             // clamp keeps counts uniform
#pragma unroll
        for (int nj = 0; nj < 2; nj++)
#pragma unroll
            for (int kk = 0; kk < 4; kk++)
                bnxt[nj][kk] = *(const uint4*)(bptr[nj] + (size_t)(tn * 4 + kk) * 512);
        const int buf = tt & 1;
        __builtin_amdgcn_s_setprio(1);
#pragma unroll
        for (int kk = 0; kk < 4; kk++) {
            const int u7 = (kk * 2 + hi) ^ x7 ^ s3;
            short8 af[4];
#pragma unroll
            for (int mi = 0; mi < 4; mi++)
                af[mi] = bc8(smemA[buf * 1024 + (mi * 32 + l31) * 8 + u7]);
#pragma unroll
            for (int mi = 0; mi < 4; mi++)
#pragma unroll
                for (int nj = 0; nj < 2; nj++)
                    acc[mi][nj] = __builtin_amdgcn_mfma_f32_32x32x16_bf16(
                        af[mi], bc8(bcur[nj][kk]), acc[mi][nj], 0, 0, 0);
        }
        __builtin_amdgcn_s_setprio(0);
        __builtin_amdgcn_s_barrier();                       // reads of A(tt) done
        __builtin_amdgcn_sched_barrier(0);
        stageA(buf, ((tt < 30) ? tt + 2 : 31) * 64);        // A(tt+2) -> freed buf
    };

    // ---- prologue: A(0),A(1) staged; B(0) in regs; counts line up at tt=0
    stageA(0, 0);
    stageA(1, 64);
    __builtin_amdgcn_sched_barrier(0);
#pragma unroll
    for (int nj = 0; nj < 2; nj++)
#pragma unroll
        for (int kk = 0; kk < 4; kk++)
            bA[nj][kk] = *(const uint4*)(bptr[nj] + (size_t)kk * 512);

#pragma unroll 1
    for (int it = 0; it < 16; ++it) {
        halfiter(2 * it,     bA, bB);
        halfiter(2 * it + 1, bB, bA);
    }

    // ---- Epilogue: bias + relu + (.)@W3[half] reduce over n, shuffle, atomics
    const int p    = nBase >> 11;          // 0: W21/W31 path, 1: W22/W32 path
    const int nloc = nBase & 2047;
    const float* b2p = (p ? b22 : b21) + (size_t)h * D_;
    const float* W3p = (p ? W32 : W31) + (size_t)h * D_ * C_;
    float* ab2 = (p ? acc32 : acc31) + (size_t)h * B_ * C_;

    float bs[2], w3x[2], w3y[2];
#pragma unroll
    for (int nj = 0; nj < 2; nj++) {
        const int e = nloc + wid * 64 + nj * 32 + l31;
        bs[nj] = b2p[e];
        const float2 w2 = *(const float2*)(W3p + e * 2);
        w3x[nj] = w2.x; w3y[nj] = w2.y;
    }
#pragma unroll
    for (int mi = 0; mi < 4; mi++)
#pragma unroll
        for (int r = 0; r < 16; r++) {
            const float v0 = fmaxf(acc[mi][0][r] + bs[0], 0.f);
            const float v1 = fmaxf(acc[mi][1][r] + bs[1], 0.f);
            float s0 = fmaf(v0, w3x[0], v1 * w3x[1]);
            float s1 = fmaf(v0, w3y[0], v1 * w3y[1]);
#pragma unroll
            for (int off = 1; off < 32; off <<= 1) {
                s0 += __shfl_xor(s0, off, 64);
                s1 += __shfl_xor(s1, off, 64);
            }
            if (l31 == 0) {
                const int row = mBase + mi * 32 + (r & 3) + 8 * (r >> 2) + 4 * hi;
                atomicAdd(&ab2[row * C_ + 0], s0);
                atomicAdd(&ab2[row * C_ + 1], s1);
            }
        }
}

// ---------------------------------------------------------------------------
// Finalize: biases, sigmoid head, CBF-QP correction, softmax-weighted mix
// ---------------------------------------------------------------------------
__global__ __launch_bounds__(256) void k_final(
    const float* __restrict__ x,
    const float* __restrict__ acc31, const float* __restrict__ acc32,
    const float* __restrict__ b31, const float* __restrict__ b32,
    const float* __restrict__ wt, const float* __restrict__ mean,
    const float* __restrict__ stdv, float* __restrict__ out)
{
    const int b = blockIdx.x * 256 + threadIdx.x;
    const float4 xb = *(const float4*)(x + (size_t)b * 4);
    const float px = xb.x * stdv[0] + mean[0];
    const float py = xb.y * stdv[1] + mean[1];
    const float th = xb.z * stdv[2] + mean[2];
    const float v  = xb.w * stdv[3] + mean[3];
    const float dx = px - 40.0f, dy = py - 15.0f;
    const float st = sinf(th), ct = cosf(th);
    const float barrier = dx * dx + dy * dy - 36.0f;
    const float bdot = 2.f * dx * v * ct + 2.f * dy * v * st;
    const float Lf2b = 2.f * v * v;
    const float G0 = -(-2.f * dx * v * st + 2.f * dy * v * ct);
    const float G1 = -(2.f * dx * ct + 2.f * dy * st);
    const float GG = G0 * G0 + G1 * G1;

    float we[H_];
    float wmax = wt[0];
    for (int h = 1; h < H_; h++) wmax = fmaxf(wmax, wt[h]);
    float wsum = 0.f;
    for (int h = 0; h < H_; h++) { we[h] = expf(wt[h] - wmax); wsum += we[h]; }

    float o0 = 0.f, o1 = 0.f;
#pragma unroll
    for (int h = 0; h < H_; h++) {
        const size_t idx = ((size_t)h * B_ + b) * 2;
        const float x310 = acc31[idx]     + b31[h * 2];
        const float x311 = acc31[idx + 1] + b31[h * 2 + 1];
        const float z0 = acc32[idx]     + b32[h * 2];
        const float z1 = acc32[idx + 1] + b32[h * 2 + 1];
        const float x320 = 4.f / (1.f + expf(-z0));
        const float x321 = 4.f / (1.f + expf(-z1));
        const float hr = Lf2b + (x320 + x321) * bdot + x320 * x321 * barrier;
        const float Gu = G0 * x310 + G1 * x311;
        const float lam = fmaxf(Gu - hr, 0.f) / GG;
        o0 += we[h] * (x310 - lam * G0);
        o1 += we[h] * (x311 - lam * G1);
    }
    out[b * 2]     = o0 / wsum;
    out[b * 2 + 1] = o1 / wsum;
}

extern "C" void kernel_launch(void* const* d_in, const int* in_sizes, int n_in,
                              void* d_out, int out_size, void* d_ws, size_t ws_size,
                              hipStream_t stream)
{
    const float* x    = (const float*)d_in[0];
    const float* W1   = (const float*)d_in[1];
    const float* b1   = (const float*)d_in[2];
    const float* W21  = (const float*)d_in[3];
    const float* b21  = (const float*)d_in[4];
    const float* W22  = (const float*)d_in[5];
    const float* b22  = (const float*)d_in[6];
    const float* W31  = (const float*)d_in[7];
    const float* b31  = (const float*)d_in[8];
    const float* W32  = (const float*)d_in[9];
    const float* b32  = (const float*)d_in[10];
    const float* wt   = (const float*)d_in[11];
    const float* mean = (const float*)d_in[12];
    const float* stdv = (const float*)d_in[13];
    float* out = (float*)d_out;

    char* ws = (char*)d_ws;
    uint16_t* Bc   = (uint16_t*)(ws);
    float* acc31   = (float*)(ws + 167772160);
    float* acc32   = (float*)(ws + 169082880);
    uint16_t* h1t  = (uint16_t*)(ws + 170393600);

    k_convert<<<dim3(32, 32, 20), 256, 0, stream>>>(W21, W22, Bc);
    k_zero<<<dim3(640), 256, 0, stream>>>((uint4*)acc31, 163840);
    for (int h = 0; h < H_; ++h) {
        k_h1<<<dim3(1024), 256, 0, stream>>>(x, W1, b1, h1t, h);
        k_gemm<<<dim3(2048), 256, 0, stream>>>(h1t, Bc, b21, b22, W31, W32,
                                               acc31, acc32, h);
    }
    k_final<<<dim3(64), 256, 0, stream>>>(x, acc31, acc32, b31, b32, wt, mean, stdv, out);
}